// Round 4
// baseline (390.166 us; speedup 1.0000x reference)
//
#include <hip/hip_runtime.h>
#include <stdint.h>

// Problem constants (B,S,D fixed by the reference)
#define B_  4
#define S_  2048
#define D_  1024
#define DK_ 1024
#define DV_ 1024

typedef __attribute__((ext_vector_type(8)))  short short8;    // 8 bf16 = 4 VGPRs (MFMA A/B frag)
typedef __attribute__((ext_vector_type(16))) float floatx16;  // 32x32 MFMA C/D frag

// async global->LDS DMA, 16B per lane, wave-uniform LDS base (lane scatters +lane*16B)
#define ASYNC16(gsrc, ldst)                                                        \
  __builtin_amdgcn_global_load_lds(                                                \
      (const __attribute__((address_space(1))) unsigned int*)(gsrc),               \
      (__attribute__((address_space(3))) unsigned int*)(ldst), 16, 0, 0)

// counted vector-memory wait: lets younger global_load_lds stay in flight (T4)
#define WAITVM(N) asm volatile("s_waitcnt vmcnt(" #N ")" ::: "memory")

// round-to-nearest-even fp32 -> bf16
__device__ __forceinline__ unsigned short f2bf(float f) {
  union { float f; uint32_t u; } v; v.f = f;
  uint32_t r = v.u + 0x7fffu + ((v.u >> 16) & 1u);
  return (unsigned short)(r >> 16);
}

// ---------------- prep: fp32->bf16 for q/k/v  +  W^T (bf16), one dispatch ----------------
__global__ __launch_bounds__(256)
void prep(const float* __restrict__ q, const float* __restrict__ k, const float* __restrict__ v,
          const float* __restrict__ W0, const float* __restrict__ W1, const float* __restrict__ W2,
          unsigned short* __restrict__ qkv, unsigned short* __restrict__ WT) {
  const int bid = blockIdx.x, tid = threadIdx.x;
  if (bid < 12288) {
    const int t  = bid >> 12;         // tensor 0..2
    const int cb = bid & 4095;        // chunk within tensor
    const float* in = (t == 0) ? q : (t == 1) ? k : v;
    unsigned short* o = qkv + (long)t * ((long)B_ * S_ * D_);
    const int i0 = cb * 512 + tid;    // float4 index (512 per block)
    float4 v0 = ((const float4*)in)[i0];
    float4 v1 = ((const float4*)in)[i0 + 256];
    ushort4 u0, u1;
    u0.x = f2bf(v0.x); u0.y = f2bf(v0.y); u0.z = f2bf(v0.z); u0.w = f2bf(v0.w);
    u1.x = f2bf(v1.x); u1.y = f2bf(v1.y); u1.z = f2bf(v1.z); u1.w = f2bf(v1.w);
    ((ushort4*)o)[i0] = u0;
    ((ushort4*)o)[i0 + 256] = u1;
  } else {
    const int b2 = bid - 12288;
    const int w  = b2 >> 10;          // weight 0..2
    const int tl = b2 & 1023;         // 32x32 tile id
    const float* in = (w == 0) ? W0 : (w == 1) ? W1 : W2;
    unsigned short* o = WT + (long)w * D_ * DK_;
    __shared__ float tile[32][33];
    const int bx = (tl & 31) * 32, by = (tl >> 5) * 32;
    const int tx = tid & 31, ty = tid >> 5;
    for (int r = ty; r < 32; r += 8)
      tile[r][tx] = in[(long)(by + r) * DK_ + bx + tx];
    __syncthreads();
    for (int r = ty; r < 32; r += 8)
      o[(long)(bx + r) * D_ + by + tx] = f2bf(tile[tx][r]);
  }
}

__device__ __forceinline__ void storeC(float* p, float v)          { *p = v; }
__device__ __forceinline__ void storeC(unsigned short* p, float v) { *p = f2bf(v); }

// ---------------- bf16 BT GEMM, 256x256 tile, 8 waves, 32x32x16 MFMA ----------------
// ROUND 10 geometry change.  Post-mortem r7-r9: MfmaUtil pinned at ~22% across THREE
//   pipeline schedules => schedule was not the constraint; the 128^2/4-wave geometry was
//   (1 KB LDS read per MFMA, LDS-port+overhead bound; matches guide m102 curve ~320 TF).
//   Now: BM=BN=256, 512 threads, 8 waves as 2Mx4N, per-wave 128x64 (acc[4][2], 128 f32),
//   frag reuse 16 MFMA per 12 ds_read_b128 per chunk.  Measured reference for this
//   geometry + 2-phase loop: 666-682 TF (m230/m248v2) vs our ~350.
// Loop: UNCHANGED round-9 3-buffer counted-vmcnt depth-2 pipeline (ran correct r3).
//   Per chunk per wave: 4 DMA lines (2A+2B).  WAITVM(4) keeps next chunk in flight.
// LDS: 3 bufs x (A 16KB + B 16KB) = 96KB -> 1 block/CU, 2 waves/SIMD.
// Swizzle (verified r6): LDS[row][q] = global[row][q ^ ((row>>1)&3)] per 64B line;
//   read back with off = ((s*2+hi) ^ ((lm>>1)&3))*8.
// A/B frag (32x32x16): m(or n)=lane&31, k-chunk=(s*2+hi).
// C/D (m74/m101 verified): col=lane&31, row=(reg&3)+8*(reg>>2)+4*(lane>>5).
// NOUT=3: fused QKV (n0g selects A/C/bias; B spans 3072 rows). sel==2 stores V
//   transposed into Vt[B][DV][S].
// MODE: 0 plain+bias; 1 store exp(val)+atomicAdd row sums; 2 x 1/rowsum store;
//   3 x 1/rowsum atomicAdd (split-K partial, out pre-zeroed).
// KSPL: K-split factor (1 or 2); z = batch*KSPL + khalf; lda/ldb = row strides.
template <typename OutT, int NOUT, int MODE, int KSPL>
__global__ __launch_bounds__(512, 2)
void gemm_bt256(const unsigned short* __restrict__ A0, const unsigned short* __restrict__ A1,
                const unsigned short* __restrict__ A2, const unsigned short* __restrict__ Bm,
                OutT* __restrict__ C0, OutT* __restrict__ C1, OutT* __restrict__ C2,
                const float* __restrict__ b0, const float* __restrict__ b1,
                const float* __restrict__ b2, float* __restrict__ rowsum,
                int N, int K, int lda, int ldb, long sA, long sB, long sC, float scale) {
  __shared__ __align__(16) unsigned short As[3][256 * 32];   // 3 pipeline buffers, 16KB each
  __shared__ __align__(16) unsigned short Bs[3][256 * 32];
  __shared__ float invs[256];
  const int tid  = threadIdx.x;
  const int lane = tid & 63, wave = tid >> 6;     // 8 waves
  const int wm = (wave >> 2) * 128;               // 2 M-waves
  const int wn = (wave & 3) * 64;                 // 4 N-waves
  const int lm = lane & 31;
  const int hi = lane >> 5;

  // ---- bijective XCD-chunk remap (8 XCDs; every grid here has total %8 == 0) ----
  const int gx = gridDim.x, gy = gridDim.y;
  const int T  = gx * gy * (int)gridDim.z;
  const int l  = blockIdx.x + gx * (blockIdx.y + gy * blockIdx.z);
  const int l2 = (l & 7) * (T >> 3) + (l >> 3);
  const int bxi = l2 % gx;
  const int byi = (l2 / gx) % gy;
  const int bzi = l2 / (gx * gy);

  const int  kh = (KSPL > 1) ? (bzi & (KSPL - 1)) : 0;
  const long zb = (KSPL > 1) ? (bzi >> 1) : bzi;
  const int m0  = byi * 256;
  const int n0g = bxi * 256;

  const unsigned short* A = A0;
  OutT* C = C0;
  const float* bias = b0;
  int n0 = n0g, sel = 0;
  if (NOUT == 3) {
    sel = n0g >> 10;
    n0 = n0g & 1023;
    if (sel == 1)      { A = A1; C = C1; bias = b1; }
    else if (sel == 2) { A = A2; C = C2; bias = b2; }
  }
  A += zb * sA + (long)kh * K;
  const unsigned short* Bp = Bm + zb * sB + (long)kh * K;
  C += zb * sC;

  // ---- staging: per wave 2 A-lines + 2 B-lines per BK=32 chunk (16-row lines) ----
  const int rr = lane >> 2;
  const int cc = (((lane & 3) ^ ((lane >> 3) & 3)) * 8);   // 64B-line XOR swizzle on source
  const unsigned short* gA0 = A  + (long)(m0  + 16 * wave + rr) * lda + cc;
  const unsigned short* gA1 = gA0 + 128 * (long)lda;
  const unsigned short* gB0 = Bp + (long)(n0g + 16 * wave + rr) * ldb + cc;
  const unsigned short* gB1 = gB0 + 128 * (long)ldb;
  const int la0 = wave * 512, la1 = (wave + 8) * 512;      // 16 rows * 32 cols per line

  floatx16 acc[4][2] = {};
  const int sw = (lm >> 1) & 3;

#define GEMM_COMPUTE(pp)                                                                \
  _Pragma("unroll")                                                                     \
  for (int s = 0; s < 2; s++) {                                                         \
    const int off = ((s * 2 + hi) ^ sw) * 8;                                            \
    short8 af[4], bf[2];                                                                \
    _Pragma("unroll")                                                                   \
    for (int i = 0; i < 4; i++)                                                         \
      af[i] = *(const short8*)&As[pp][(wm + i * 32 + lm) * 32 + off];                   \
    _Pragma("unroll")                                                                   \
    for (int j = 0; j < 2; j++)                                                         \
      bf[j] = *(const short8*)&Bs[pp][(wn + j * 32 + lm) * 32 + off];                   \
    _Pragma("unroll")                                                                   \
    for (int i = 0; i < 4; i++)                                                         \
      _Pragma("unroll")                                                                 \
      for (int j = 0; j < 2; j++)                                                       \
        acc[i][j] = __builtin_amdgcn_mfma_f32_32x32x16_bf16(af[i], bf[j], acc[i][j], 0, 0, 0); \
  }

  // ---- prologue: stage chunks 0,1 into buffers 0,1 (8 loads/thread in flight) ----
  ASYNC16(gA0, &As[0][la0]); ASYNC16(gA1, &As[0][la1]);
  ASYNC16(gB0, &Bs[0][la0]); ASYNC16(gB1, &Bs[0][la1]);
  gA0 += 32; gA1 += 32; gB0 += 32; gB1 += 32;
  ASYNC16(gA0, &As[1][la0]); ASYNC16(gA1, &As[1][la1]);
  ASYNC16(gB0, &Bs[1][la0]); ASYNC16(gB1, &Bs[1][la1]);
  gA0 += 32; gA1 += 32; gB0 += 32; gB1 += 32;

  // ---- main loop: one barrier per chunk, vmcnt(4) counted wait, depth-2 in flight ----
  const int nk = K >> 5;
  int pc = 0, pn = 2;
  for (int kt = 0; kt < nk - 1; kt++) {
    WAITVM(4);                       // chunk kt's 4 loads done; kt+1's stay in flight
    __builtin_amdgcn_s_barrier();    // all waves' chunk-kt DMAs landed
    if (kt + 2 < nk) {               // issue chunk kt+2 into buffer that held chunk kt-1
      ASYNC16(gA0, &As[pn][la0]); ASYNC16(gA1, &As[pn][la1]);
      ASYNC16(gB0, &Bs[pn][la0]); ASYNC16(gB1, &Bs[pn][la1]);
      gA0 += 32; gA1 += 32; gB0 += 32; gB1 += 32;
    }
    GEMM_COMPUTE(pc)
    pc = (pc == 2) ? 0 : pc + 1;
    pn = (pn == 2) ? 0 : pn + 1;
  }
  WAITVM(0);                         // last chunk: nothing younger in flight
  __builtin_amdgcn_s_barrier();
  GEMM_COMPUTE(pc)

  // ---- MODE 2/3: stage 1/rowsum for this block's 256 rows ----
  if (MODE == 2 || MODE == 3) {
    __syncthreads();
    if (tid < 256) invs[tid] = 1.0f / rowsum[zb * S_ + m0 + tid];
    __syncthreads();
  }

  // ---- epilogue: C/D col=lane&31, row=(r&3)+8*(r>>2)+4*hi ----
  if (NOUT == 3 && sel == 2) {
    // V output, stored transposed into Vt[B][DV][S]
    unsigned short* Vt = (unsigned short*)C;
    const int b = m0 >> 11;              // batch (2048 rows per batch; 256 | 2048)
    const int sbase = (m0 & 2047);
#pragma unroll
    for (int i = 0; i < 4; i++) {
      const int srowb = sbase + wm + i * 32 + (hi << 2);
#pragma unroll
      for (int j = 0; j < 2; j++) {
        const int col = n0 + wn + j * 32 + lm;
        const float bv = bias[col];
        unsigned short* vp = Vt + ((long)b * DV_ + col) * S_ + srowb;
#pragma unroll
        for (int g = 0; g < 4; g++) {
          ushort4 u;
          u.x = f2bf(acc[i][j][4 * g + 0] + bv);
          u.y = f2bf(acc[i][j][4 * g + 1] + bv);
          u.z = f2bf(acc[i][j][4 * g + 2] + bv);
          u.w = f2bf(acc[i][j][4 * g + 3] + bv);
          *(ushort4*)(vp + 8 * g) = u;
        }
      }
    }
  } else if (MODE == 1) {
    // scores: store U = exp(score), accumulate row sums (shfl-reduce + 1 atomic per 32 lanes)
#pragma unroll
    for (int i = 0; i < 4; i++) {
#pragma unroll
      for (int r = 0; r < 16; r++) {
        const int row = m0 + wm + i * 32 + (r & 3) + ((r >> 2) << 3) + (hi << 2);
        float sum2 = 0.f;
#pragma unroll
        for (int j = 0; j < 2; j++) {
          const int col = n0 + wn + j * 32 + lm;
          float e = __expf(acc[i][j][r] * scale);
          storeC(C + (long)row * N + col, e);
          sum2 += e;
        }
#pragma unroll
        for (int msk = 1; msk < 32; msk <<= 1) sum2 += __shfl_xor(sum2, msk, 64);
        if ((lane & 31) == 0) atomicAdd(&rowsum[zb * S_ + row], sum2);
      }
    }
  } else {
#pragma unroll
    for (int i = 0; i < 4; i++) {
#pragma unroll
      for (int j = 0; j < 2; j++) {
        const int col = n0 + wn + j * 32 + lm;
        const float bv = bias ? bias[col] : 0.f;
#pragma unroll
        for (int r = 0; r < 16; r++) {
          const int rl = wm + i * 32 + (r & 3) + ((r >> 2) << 3) + (hi << 2);
          float val = acc[i][j][r] * scale + bv;
          if (MODE == 3) {
            atomicAdd((float*)(C + (long)(m0 + rl) * N + col), val * invs[rl]);
          } else {
            if (MODE == 2) val *= invs[rl];
            storeC(C + (long)(m0 + rl) * N + col, val);
          }
        }
      }
    }
  }
#undef GEMM_COMPUTE
}

extern "C" void kernel_launch(void* const* d_in, const int* in_sizes, int n_in,
                              void* d_out, int out_size, void* d_ws, size_t ws_size,
                              hipStream_t stream) {
  const float* q_in = (const float*)d_in[0];
  const float* k_in = (const float*)d_in[1];
  const float* v_in = (const float*)d_in[2];
  const float* Wq   = (const float*)d_in[3];
  const float* bq   = (const float*)d_in[4];
  const float* Wk   = (const float*)d_in[5];
  const float* bk   = (const float*)d_in[6];
  const float* Wv   = (const float*)d_in[7];
  const float* bv   = (const float*)d_in[8];
  float* out = (float*)d_out;

  // ---- workspace layout; U (bf16 scores) overlays dead qb/kb/vb after QKV ----
  char* ws = (char*)d_ws;
  const long nX = (long)B_ * S_ * D_;   // 8388608 elems
  const long nW = (long)D_ * DK_;       // 1048576
  unsigned short* qb  = (unsigned short*)(ws);
  unsigned short* kb  = qb + nX;
  unsigned short* vb  = kb + nX;
  unsigned short* WqT = vb + nX;        // 3 contiguous = B[3072,1024]
  unsigned short* Qb  = WqT + 3 * nW;
  unsigned short* Kb  = Qb + nX;
  unsigned short* Vt  = Kb + nX;        // [B, DV, S] written directly by QKV epilogue
  float*          rowsum = (float*)(Vt + nX);     // B*S fp32 = 32KB
  unsigned short* U   = (unsigned short*)ws;      // bf16 [B,S,S] overlay (qb/kb/vb dead)

  dim3 blk(256), blk5(512);

  // 0) zero rowsum + out (out receives split-K atomicAdd partials)
  hipMemsetAsync(rowsum, 0, (size_t)B_ * S_ * sizeof(float), stream);
  hipMemsetAsync(out, 0, (size_t)B_ * S_ * DV_ * sizeof(float), stream);

  // 1) prep: q/k/v -> bf16 and W -> W^T bf16, one dispatch
  {
    dim3 g(12288 + 3072);
    prep<<<g, blk, 0, stream>>>(q_in, k_in, v_in, Wq, Wk, Wv, qb, WqT);
  }
  // 2) fused QKV projection; V stored transposed into Vt.  grid 12x32 = 384 blocks
  {
    dim3 g(3 * DK_ / 256, (B_ * S_) / 256, 1);
    gemm_bt256<unsigned short, 3, 0, 1><<<g, blk5, 0, stream>>>(
        qb, kb, vb, WqT, Qb, Kb, Vt, bq, bk, bv, nullptr,
        DK_, D_, D_, D_, 0, 0, 0, 1.f);
  }
  // 3) U = exp(Q K^T / 32) -> bf16, + per-row sums.  grid 8x8x4 = 256 blocks (1/CU)
  {
    dim3 g(S_ / 256, S_ / 256, B_);
    gemm_bt256<unsigned short, 1, 1, 1><<<g, blk5, 0, stream>>>(
        Qb, nullptr, nullptr, Kb, U, nullptr, nullptr, nullptr, nullptr, nullptr, rowsum,
        S_, DK_, DK_, DK_, (long)S_ * DK_, (long)S_ * DK_, (long)S_ * S_, 0.03125f);
  }
  // 4) out += (U_khalf @ V_khalf) / rowsum, split-K=2.  grid 4x8x8 = 256 blocks (1/CU)
  //    K slice 1024, row strides stay S_; z = batch*2 + khalf; exactly 2 atomic adds/elem.
  {
    dim3 g(DV_ / 256, S_ / 256, B_ * 2);
    gemm_bt256<float, 1, 3, 2><<<g, blk5, 0, stream>>>(
        U, nullptr, nullptr, Vt, out, nullptr, nullptr, nullptr, nullptr, nullptr, rowsum,
        DV_, S_ / 2, S_, S_, (long)S_ * S_, (long)DV_ * S_, (long)S_ * DV_, 1.f);
  }
}

// Round 5
// 377.174 us; speedup vs baseline: 1.0344x; 1.0344x over previous
//
#include <hip/hip_runtime.h>
#include <stdint.h>

// Problem constants (B,S,D fixed by the reference)
#define B_  4
#define S_  2048
#define D_  1024
#define DK_ 1024
#define DV_ 1024

typedef __attribute__((ext_vector_type(8)))  short short8;    // 8 bf16 = 4 VGPRs (MFMA A/B frag)
typedef __attribute__((ext_vector_type(16))) float floatx16;  // 32x32 MFMA C/D frag

// async global->LDS DMA, 16B per lane, wave-uniform LDS base (lane scatters +lane*16B)
#define ASYNC16(gsrc, ldst)                                                        \
  __builtin_amdgcn_global_load_lds(                                                \
      (const __attribute__((address_space(1))) unsigned int*)(gsrc),               \
      (__attribute__((address_space(3))) unsigned int*)(ldst), 16, 0, 0)

#define WAITVM(N) asm volatile("s_waitcnt vmcnt(" #N ")" ::: "memory")

// round-to-nearest-even fp32 -> bf16
__device__ __forceinline__ unsigned short f2bf(float f) {
  union { float f; uint32_t u; } v; v.f = f;
  uint32_t r = v.u + 0x7fffu + ((v.u >> 16) & 1u);
  return (unsigned short)(r >> 16);
}

// ---------------- prep: fp32->bf16 for q/k/v  +  W^T (bf16), one dispatch ----------------
__global__ __launch_bounds__(256)
void prep(const float* __restrict__ q, const float* __restrict__ k, const float* __restrict__ v,
          const float* __restrict__ W0, const float* __restrict__ W1, const float* __restrict__ W2,
          unsigned short* __restrict__ qkv, unsigned short* __restrict__ WT) {
  const int bid = blockIdx.x, tid = threadIdx.x;
  if (bid < 12288) {
    const int t  = bid >> 12;         // tensor 0..2
    const int cb = bid & 4095;        // chunk within tensor
    const float* in = (t == 0) ? q : (t == 1) ? k : v;
    unsigned short* o = qkv + (long)t * ((long)B_ * S_ * D_);
    const int i0 = cb * 512 + tid;    // float4 index (512 per block)
    float4 v0 = ((const float4*)in)[i0];
    float4 v1 = ((const float4*)in)[i0 + 256];
    ushort4 u0, u1;
    u0.x = f2bf(v0.x); u0.y = f2bf(v0.y); u0.z = f2bf(v0.z); u0.w = f2bf(v0.w);
    u1.x = f2bf(v1.x); u1.y = f2bf(v1.y); u1.z = f2bf(v1.z); u1.w = f2bf(v1.w);
    ((ushort4*)o)[i0] = u0;
    ((ushort4*)o)[i0 + 256] = u1;
  } else {
    const int b2 = bid - 12288;
    const int w  = b2 >> 10;          // weight 0..2
    const int tl = b2 & 1023;         // 32x32 tile id
    const float* in = (w == 0) ? W0 : (w == 1) ? W1 : W2;
    unsigned short* o = WT + (long)w * D_ * DK_;
    __shared__ float tile[32][33];
    const int bx = (tl & 31) * 32, by = (tl >> 5) * 32;
    const int tx = tid & 31, ty = tid >> 5;
    for (int r = ty; r < 32; r += 8)
      tile[r][tx] = in[(long)(by + r) * DK_ + bx + tx];
    __syncthreads();
    for (int r = ty; r < 32; r += 8)
      o[(long)(bx + r) * D_ + by + tx] = f2bf(tile[tx][r]);
  }
}

__device__ __forceinline__ void storeC(float* p, float v)          { *p = v; }
__device__ __forceinline__ void storeC(unsigned short* p, float v) { *p = f2bf(v); }

// ---------------- bf16 BT GEMM, 256x256 tile, 8 waves, 4-phase/K-tile schedule ----------------
// ROUND 11: fine-grained phase interleave (the 8-phase template, T3+T4+T5), ported to the
//   existing 256^2 / 8-wave / 32x32x16 geometry so epilogues stay byte-identical to r10 (passed).
//   Post-mortem r7-r10: MfmaUtil pinned at ~22% across 4 schedule/geometry configs — exactly
//   guide m196/m233: coarse chunk-granularity {issue,wait,barrier,compute} serializes; the
//   measured escape is per-phase {ds_read || stage || MFMA-cluster} interleave (m248v2:
//   2ph=666 TF vs 8ph=848 TF at 256^2/K=1024; m201: 1563 @4k).
// Structure: BK=64 K-tiles, dbuf As/Bs[2] (128KB). 4 phases per K-tile, phase q:
//   { 8x ds_read_b128 (frags for quadrant q of buf p); q==0: 4 A-DMAs, q==1: 4 B-DMAs
//     (tile t+1 -> buf p^1); s_barrier; lgkmcnt(0); setprio(1); 8 MFMA; setprio(0);
//     q==3: vmcnt(0) (tile t+1 resident; in-flight == exactly-needed); s_barrier }
//   Quadrant q = (i-pair (q>>1), s-pair (q&1)): A frags read once/tile, B twice.
// Race audit: staging into p^1 during tile t is safe — every wave's p^1 ds_reads (tile t-1)
//   drained by its phase lgkmcnt(0) before its MFMAs, which precede the barrier the staging
//   wave has passed.  Boundary vmcnt(0)+barrier publishes p^1 before tile t+1 reads it.
// Swizzle (both-sides involution, rule 21): DMA source slot = slot ^ (row&7) within the
//   128B row; read offset = ((s*2+hi) ^ (lm&7))*8.  ~4-way residual (same as st_16x32).
// A/B frag (32x32x16): m(or n)=lane&31, k-16B-chunk g=(s*2+hi), s in 0..3 over BK=64.
// C/D (m74/m101 verified): col=lane&31, row=(reg&3)+8*(reg>>2)+4*(lane>>5).
// NOUT=3: fused QKV (n0g selects A/C/bias).  sel==2 stores V transposed into Vt[B][DV][S].
// MODE: 0 plain+bias; 1 store exp(val)+atomicAdd row sums; 2 x 1/rowsum store;
//   3 x 1/rowsum atomicAdd (split-K partial, out pre-zeroed).
template <typename OutT, int NOUT, int MODE, int KSPL>
__global__ __launch_bounds__(512, 2)
void gemm_bt256(const unsigned short* __restrict__ A0, const unsigned short* __restrict__ A1,
                const unsigned short* __restrict__ A2, const unsigned short* __restrict__ Bm,
                OutT* __restrict__ C0, OutT* __restrict__ C1, OutT* __restrict__ C2,
                const float* __restrict__ b0, const float* __restrict__ b1,
                const float* __restrict__ b2, float* __restrict__ rowsum,
                int N, int K, int lda, int ldb, long sA, long sB, long sC, float scale) {
  __shared__ __align__(16) unsigned short As[2][256 * 64];   // dbuf, 32KB each
  __shared__ __align__(16) unsigned short Bs[2][256 * 64];
  __shared__ float invs[256];
  const int tid  = threadIdx.x;
  const int lane = tid & 63, wave = tid >> 6;     // 8 waves
  const int wm = (wave >> 2) * 128;               // 2 M-waves
  const int wn = (wave & 3) * 64;                 // 4 N-waves
  const int lm = lane & 31;
  const int hi = lane >> 5;

  // ---- bijective XCD-chunk remap (8 XCDs; every grid here has total %8 == 0) ----
  const int gx = gridDim.x, gy = gridDim.y;
  const int T  = gx * gy * (int)gridDim.z;
  const int l  = blockIdx.x + gx * (blockIdx.y + gy * blockIdx.z);
  const int l2 = (l & 7) * (T >> 3) + (l >> 3);
  const int bxi = l2 % gx;
  const int byi = (l2 / gx) % gy;
  const int bzi = l2 / (gx * gy);

  const int  kh = (KSPL > 1) ? (bzi & (KSPL - 1)) : 0;
  const long zb = (KSPL > 1) ? (bzi >> 1) : bzi;
  const int m0  = byi * 256;
  const int n0g = bxi * 256;

  const unsigned short* A = A0;
  OutT* C = C0;
  const float* bias = b0;
  int n0 = n0g, sel = 0;
  if (NOUT == 3) {
    sel = n0g >> 10;
    n0 = n0g & 1023;
    if (sel == 1)      { A = A1; C = C1; bias = b1; }
    else if (sel == 2) { A = A2; C = C2; bias = b2; }
  }
  A += zb * sA + (long)kh * K;
  const unsigned short* Bp = Bm + zb * sB + (long)kh * K;
  C += zb * sC;

  // ---- staging: wave w owns rows [32w,32w+32) of A and B; 4 DMAs each (8 rows/DMA) ----
  // lane L -> row 8a+(L>>3), 16B-slot (L&7); source slot XOR (row&7) = (L>>3)
  const int srow  = lane >> 3;
  const int sslot = ((lane & 7) ^ srow) * 8;
  const unsigned short* gA = A  + (long)(m0  + 32 * wave + srow) * lda + sslot;
  const unsigned short* gB = Bp + (long)(n0g + 32 * wave + srow) * ldb + sslot;
  const int lb = wave * 2048;                      // 32 rows * 64 cols per wave region

  floatx16 acc[4][2] = {};
  const int swz = lm & 7;

  const int nt = K >> 6;                           // BK=64 tiles

  // ---- prologue: stage tile 0 into buf 0, drain, publish ----
#pragma unroll
  for (int a = 0; a < 4; a++) ASYNC16(gA + (long)(8 * a) * lda, &As[0][lb + a * 512]);
#pragma unroll
  for (int a = 0; a < 4; a++) ASYNC16(gB + (long)(8 * a) * ldb, &Bs[0][lb + a * 512]);
  gA += 64; gB += 64;
  WAITVM(0);
  __builtin_amdgcn_s_barrier();

  // ---- main loop: 4 phases per K-tile ----
  for (int t = 0; t < nt; t++) {
    const int p = t & 1;
    const bool pre = (t + 1 < nt);
#pragma unroll
    for (int q = 0; q < 4; q++) {
      const int i0 = (q >> 1) * 2;                 // i-pair
      const int s0 = (q & 1) * 2;                  // s-pair
      short8 af[2][2], bf[2][2];
#pragma unroll
      for (int i = 0; i < 2; i++)
#pragma unroll
        for (int s = 0; s < 2; s++)
          af[i][s] = *(const short8*)
            &As[p][(wm + (i0 + i) * 32 + lm) * 64 + ((((s0 + s) * 2 + hi) ^ swz) * 8)];
#pragma unroll
      for (int j = 0; j < 2; j++)
#pragma unroll
        for (int s = 0; s < 2; s++)
          bf[j][s] = *(const short8*)
            &Bs[p][(wn + j * 32 + lm) * 64 + ((((s0 + s) * 2 + hi) ^ swz) * 8)];
      if (q == 0 && pre) {
#pragma unroll
        for (int a = 0; a < 4; a++) ASYNC16(gA + (long)(8 * a) * lda, &As[p ^ 1][lb + a * 512]);
      }
      if (q == 1 && pre) {
#pragma unroll
        for (int a = 0; a < 4; a++) ASYNC16(gB + (long)(8 * a) * ldb, &Bs[p ^ 1][lb + a * 512]);
        gA += 64; gB += 64;
      }
      __builtin_amdgcn_s_barrier();
      asm volatile("s_waitcnt lgkmcnt(0)" ::: "memory");
      __builtin_amdgcn_s_setprio(1);
#pragma unroll
      for (int s = 0; s < 2; s++)
#pragma unroll
        for (int i = 0; i < 2; i++)
#pragma unroll
          for (int j = 0; j < 2; j++)
            acc[i0 + i][j] =
                __builtin_amdgcn_mfma_f32_32x32x16_bf16(af[i][s], bf[j][s], acc[i0 + i][j], 0, 0, 0);
      __builtin_amdgcn_s_setprio(0);
      if (q == 3) WAITVM(0);                       // tile t+1 fully resident (no-op on last)
      __builtin_amdgcn_s_barrier();
    }
  }

  // ---- MODE 2/3: stage 1/rowsum for this block's 256 rows ----
  if (MODE == 2 || MODE == 3) {
    __syncthreads();
    if (tid < 256) invs[tid] = 1.0f / rowsum[zb * S_ + m0 + tid];
    __syncthreads();
  }

  // ---- epilogue: C/D col=lane&31, row=(r&3)+8*(r>>2)+4*hi ----
  if (NOUT == 3 && sel == 2) {
    // V output, stored transposed into Vt[B][DV][S]
    unsigned short* Vt = (unsigned short*)C;
    const int b = m0 >> 11;              // batch (2048 rows per batch; 256 | 2048)
    const int sbase = (m0 & 2047);
#pragma unroll
    for (int i = 0; i < 4; i++) {
      const int srowb = sbase + wm + i * 32 + (hi << 2);
#pragma unroll
      for (int j = 0; j < 2; j++) {
        const int col = n0 + wn + j * 32 + lm;
        const float bv = bias[col];
        unsigned short* vp = Vt + ((long)b * DV_ + col) * S_ + srowb;
#pragma unroll
        for (int g = 0; g < 4; g++) {
          ushort4 u;
          u.x = f2bf(acc[i][j][4 * g + 0] + bv);
          u.y = f2bf(acc[i][j][4 * g + 1] + bv);
          u.z = f2bf(acc[i][j][4 * g + 2] + bv);
          u.w = f2bf(acc[i][j][4 * g + 3] + bv);
          *(ushort4*)(vp + 8 * g) = u;
        }
      }
    }
  } else if (MODE == 1) {
    // scores: store U = exp(score), accumulate row sums (shfl-reduce + 1 atomic per 32 lanes)
#pragma unroll
    for (int i = 0; i < 4; i++) {
#pragma unroll
      for (int r = 0; r < 16; r++) {
        const int row = m0 + wm + i * 32 + (r & 3) + ((r >> 2) << 3) + (hi << 2);
        float sum2 = 0.f;
#pragma unroll
        for (int j = 0; j < 2; j++) {
          const int col = n0 + wn + j * 32 + lm;
          float e = __expf(acc[i][j][r] * scale);
          storeC(C + (long)row * N + col, e);
          sum2 += e;
        }
#pragma unroll
        for (int msk = 1; msk < 32; msk <<= 1) sum2 += __shfl_xor(sum2, msk, 64);
        if ((lane & 31) == 0) atomicAdd(&rowsum[zb * S_ + row], sum2);
      }
    }
  } else {
#pragma unroll
    for (int i = 0; i < 4; i++) {
#pragma unroll
      for (int j = 0; j < 2; j++) {
        const int col = n0 + wn + j * 32 + lm;
        const float bv = bias ? bias[col] : 0.f;
#pragma unroll
        for (int r = 0; r < 16; r++) {
          const int rl = wm + i * 32 + (r & 3) + ((r >> 2) << 3) + (hi << 2);
          float val = acc[i][j][r] * scale + bv;
          if (MODE == 3) {
            atomicAdd((float*)(C + (long)(m0 + rl) * N + col), val * invs[rl]);
          } else {
            if (MODE == 2) val *= invs[rl];
            storeC(C + (long)(m0 + rl) * N + col, val);
          }
        }
      }
    }
  }
}

extern "C" void kernel_launch(void* const* d_in, const int* in_sizes, int n_in,
                              void* d_out, int out_size, void* d_ws, size_t ws_size,
                              hipStream_t stream) {
  const float* q_in = (const float*)d_in[0];
  const float* k_in = (const float*)d_in[1];
  const float* v_in = (const float*)d_in[2];
  const float* Wq   = (const float*)d_in[3];
  const float* bq   = (const float*)d_in[4];
  const float* Wk   = (const float*)d_in[5];
  const float* bk   = (const float*)d_in[6];
  const float* Wv   = (const float*)d_in[7];
  const float* bv   = (const float*)d_in[8];
  float* out = (float*)d_out;

  // ---- workspace layout; U (bf16 scores) overlays dead qb/kb/vb after QKV ----
  char* ws = (char*)d_ws;
  const long nX = (long)B_ * S_ * D_;   // 8388608 elems
  const long nW = (long)D_ * DK_;       // 1048576
  unsigned short* qb  = (unsigned short*)(ws);
  unsigned short* kb  = qb + nX;
  unsigned short* vb  = kb + nX;
  unsigned short* WqT = vb + nX;        // 3 contiguous = B[3072,1024]
  unsigned short* Qb  = WqT + 3 * nW;
  unsigned short* Kb  = Qb + nX;
  unsigned short* Vt  = Kb + nX;        // [B, DV, S] written directly by QKV epilogue
  float*          rowsum = (float*)(Vt + nX);     // B*S fp32 = 32KB
  unsigned short* U   = (unsigned short*)ws;      // bf16 [B,S,S] overlay (qb/kb/vb dead)

  dim3 blk(256), blk5(512);

  // 0) zero rowsum + out (out receives split-K atomicAdd partials)
  hipMemsetAsync(rowsum, 0, (size_t)B_ * S_ * sizeof(float), stream);
  hipMemsetAsync(out, 0, (size_t)B_ * S_ * DV_ * sizeof(float), stream);

  // 1) prep: q/k/v -> bf16 and W -> W^T bf16, one dispatch
  {
    dim3 g(12288 + 3072);
    prep<<<g, blk, 0, stream>>>(q_in, k_in, v_in, Wq, Wk, Wv, qb, WqT);
  }
  // 2) fused QKV projection; V stored transposed into Vt.  grid 12x32 = 384 blocks
  {
    dim3 g(3 * DK_ / 256, (B_ * S_) / 256, 1);
    gemm_bt256<unsigned short, 3, 0, 1><<<g, blk5, 0, stream>>>(
        qb, kb, vb, WqT, Qb, Kb, Vt, bq, bk, bv, nullptr,
        DK_, D_, D_, D_, 0, 0, 0, 1.f);
  }
  // 3) U = exp(Q K^T / 32) -> bf16, + per-row sums.  grid 8x8x4 = 256 blocks (1/CU)
  {
    dim3 g(S_ / 256, S_ / 256, B_);
    gemm_bt256<unsigned short, 1, 1, 1><<<g, blk5, 0, stream>>>(
        Qb, nullptr, nullptr, Kb, U, nullptr, nullptr, nullptr, nullptr, nullptr, rowsum,
        S_, DK_, DK_, DK_, (long)S_ * DK_, (long)S_ * DK_, (long)S_ * S_, 0.03125f);
  }
  // 4) out += (U_khalf @ V_khalf) / rowsum, split-K=2.  grid 4x8x8 = 256 blocks (1/CU)
  {
    dim3 g(DV_ / 256, S_ / 256, B_ * 2);
    gemm_bt256<float, 1, 3, 2><<<g, blk5, 0, stream>>>(
        U, nullptr, nullptr, Vt, out, nullptr, nullptr, nullptr, nullptr, nullptr, rowsum,
        DV_, S_ / 2, S_, S_, (long)S_ * S_, (long)DV_ * S_, (long)S_ * DV_, 1.f);
  }
}

// Round 6
// 373.994 us; speedup vs baseline: 1.0432x; 1.0085x over previous
//
#include <hip/hip_runtime.h>
#include <stdint.h>

// Problem constants (B,S,D fixed by the reference)
#define B_  4
#define S_  2048
#define D_  1024
#define DK_ 1024
#define DV_ 1024

typedef __attribute__((ext_vector_type(8)))  short short8;    // 8 bf16 = 4 VGPRs (MFMA A/B frag)
typedef __attribute__((ext_vector_type(16))) float floatx16;  // 32x32 MFMA C/D frag

// async global->LDS DMA, 16B per lane, wave-uniform LDS base (lane scatters +lane*16B)
#define ASYNC16(gsrc, ldst)                                                        \
  __builtin_amdgcn_global_load_lds(                                                \
      (const __attribute__((address_space(1))) unsigned int*)(gsrc),               \
      (__attribute__((address_space(3))) unsigned int*)(ldst), 16, 0, 0)

#define WAITVM(N) asm volatile("s_waitcnt vmcnt(" #N ")" ::: "memory")

// round-to-nearest-even fp32 -> bf16
__device__ __forceinline__ unsigned short f2bf(float f) {
  union { float f; uint32_t u; } v; v.f = f;
  uint32_t r = v.u + 0x7fffu + ((v.u >> 16) & 1u);
  return (unsigned short)(r >> 16);
}

// ---------------- prep: fp32->bf16 for q/k/v  +  W^T (bf16), one dispatch ----------------
__global__ __launch_bounds__(256)
void prep(const float* __restrict__ q, const float* __restrict__ k, const float* __restrict__ v,
          const float* __restrict__ W0, const float* __restrict__ W1, const float* __restrict__ W2,
          unsigned short* __restrict__ qkv, unsigned short* __restrict__ WT) {
  const int bid = blockIdx.x, tid = threadIdx.x;
  if (bid < 12288) {
    const int t  = bid >> 12;         // tensor 0..2
    const int cb = bid & 4095;        // chunk within tensor
    const float* in = (t == 0) ? q : (t == 1) ? k : v;
    unsigned short* o = qkv + (long)t * ((long)B_ * S_ * D_);
    const int i0 = cb * 512 + tid;    // float4 index (512 per block)
    float4 v0 = ((const float4*)in)[i0];
    float4 v1 = ((const float4*)in)[i0 + 256];
    ushort4 u0, u1;
    u0.x = f2bf(v0.x); u0.y = f2bf(v0.y); u0.z = f2bf(v0.z); u0.w = f2bf(v0.w);
    u1.x = f2bf(v1.x); u1.y = f2bf(v1.y); u1.z = f2bf(v1.z); u1.w = f2bf(v1.w);
    ((ushort4*)o)[i0] = u0;
    ((ushort4*)o)[i0 + 256] = u1;
  } else {
    const int b2 = bid - 12288;
    const int w  = b2 >> 10;          // weight 0..2
    const int tl = b2 & 1023;         // 32x32 tile id
    const float* in = (w == 0) ? W0 : (w == 1) ? W1 : W2;
    unsigned short* o = WT + (long)w * D_ * DK_;
    __shared__ float tile[32][33];
    const int bx = (tl & 31) * 32, by = (tl >> 5) * 32;
    const int tx = tid & 31, ty = tid >> 5;
    for (int r = ty; r < 32; r += 8)
      tile[r][tx] = in[(long)(by + r) * DK_ + bx + tx];
    __syncthreads();
    for (int r = ty; r < 32; r += 8)
      o[(long)(bx + r) * D_ + by + tx] = f2bf(tile[tx][r]);
  }
}

__device__ __forceinline__ void storeC(float* p, float v)          { *p = v; }
__device__ __forceinline__ void storeC(unsigned short* p, float v) { *p = f2bf(v); }

// ---------------- bf16 BT GEMM, 256x256 tile, 8 waves, 3-buf ring, counted vmcnt ----------------
// ROUND 12: first variant with ALL measured levers present simultaneously:
//   fine per-phase interleave (m196) + counted vmcnt NEVER 0 in loop (m218/T4) +
//   64B-line swizzle (r6-verified) + setprio around MFMA clusters (T5).
// Post-mortem r11: my q3 vmcnt(0) per tile = "8-phase with drain0" == 2-phase (m218 predicted
//   the null).  dbuf-2 cannot give >1-tile lookahead (staging collides with consumed buffer),
//   so: BK=32 K-tiles, THREE buffer ring.  Tile t reads buf t%3, t+1 resident in (t+1)%3,
//   t+2 streams into (t+2)%3 — disjoint; DMAs get >=4 phases (~2000cy) to land.
// Per tile, 2 phases:
//   ph0: ds_read af(i-pair 0) 4x + bf(all) 4x; stage A(t+2) (2 DMA); barrier; lgkm(0);
//        setprio1; 8 MFMA (acc[0..1][*]); setprio0; barrier
//   ph1: ds_read af2(i-pair 1) 4x (bf carried in regs); stage B(t+2) (2 DMA); barrier;
//        lgkm(0); setprio1; 8 MFMA (acc[2..3][*]); setprio0;
//        WAITVM(4) if t+2<nt else WAITVM(0); barrier
// vmcnt(4): at end of tile t outstanding = t+1's 4 + t+2's 4; leaves t+2's in flight,
//   retires t+1's => t+1 publishable by trailing barrier.  Tail: vmcnt(0) (r11-style
//   off-by-one would leave the last tile unpublished).
// Swizzle (r6-verified): LDS[row][q16] = global[row][q16 ^ ((row>>1)&3)] within 64B line;
//   write key (lane>>3)&3 (row=lane>>2), read off=((s*2+hi)^((lm>>1)&3))*8.
// A/B frag (32x32x16): m(or n)=lane&31, k-chunk=(s*2+hi).
// C/D (m74/m101 verified): col=lane&31, row=(reg&3)+8*(reg>>2)+4*(lane>>5).
// NOUT=3: fused QKV (n0g selects A/C/bias).  sel==2 stores V transposed into Vt[B][DV][S].
// MODE: 0 plain+bias; 1 store exp(val)+atomicAdd row sums; 2 x 1/rowsum store;
//   3 x 1/rowsum atomicAdd (split-K partial, out pre-zeroed).
template <typename OutT, int NOUT, int MODE, int KSPL>
__global__ __launch_bounds__(512, 2)
void gemm_bt256(const unsigned short* __restrict__ A0, const unsigned short* __restrict__ A1,
                const unsigned short* __restrict__ A2, const unsigned short* __restrict__ Bm,
                OutT* __restrict__ C0, OutT* __restrict__ C1, OutT* __restrict__ C2,
                const float* __restrict__ b0, const float* __restrict__ b1,
                const float* __restrict__ b2, float* __restrict__ rowsum,
                int N, int K, int lda, int ldb, long sA, long sB, long sC, float scale) {
  __shared__ __align__(16) unsigned short As[3][256 * 32];   // 16KB per buf
  __shared__ __align__(16) unsigned short Bs[3][256 * 32];
  __shared__ float invs[256];
  const int tid  = threadIdx.x;
  const int lane = tid & 63, wave = tid >> 6;     // 8 waves
  const int wm = (wave >> 2) * 128;               // 2 M-waves
  const int wn = (wave & 3) * 64;                 // 4 N-waves
  const int lm = lane & 31;
  const int hi = lane >> 5;

  // ---- bijective XCD-chunk remap (8 XCDs; every grid here has total %8 == 0) ----
  const int gx = gridDim.x, gy = gridDim.y;
  const int T  = gx * gy * (int)gridDim.z;
  const int l  = blockIdx.x + gx * (blockIdx.y + gy * blockIdx.z);
  const int l2 = (l & 7) * (T >> 3) + (l >> 3);
  const int bxi = l2 % gx;
  const int byi = (l2 / gx) % gy;
  const int bzi = l2 / (gx * gy);

  const int  kh = (KSPL > 1) ? (bzi & (KSPL - 1)) : 0;
  const long zb = (KSPL > 1) ? (bzi >> 1) : bzi;
  const int m0  = byi * 256;
  const int n0g = bxi * 256;

  const unsigned short* A = A0;
  OutT* C = C0;
  const float* bias = b0;
  int n0 = n0g, sel = 0;
  if (NOUT == 3) {
    sel = n0g >> 10;
    n0 = n0g & 1023;
    if (sel == 1)      { A = A1; C = C1; bias = b1; }
    else if (sel == 2) { A = A2; C = C2; bias = b2; }
  }
  A += zb * sA + (long)kh * K;
  const unsigned short* Bp = Bm + zb * sB + (long)kh * K;
  C += zb * sC;

  // ---- staging: wave w owns rows [32w,32w+32); 2 DMAs per matrix per tile (16 rows each) ----
  // lane L -> row (L>>2), 16B-slot (L&3) ^ ((L>>3)&3)  [= (row>>1)&3, r6-verified]
  const int rr = lane >> 2;
  const int cc = (((lane & 3) ^ ((lane >> 3) & 3)) * 8);
  const unsigned short* gA0 = A  + (long)(m0  + 32 * wave + rr) * lda + cc;
  const unsigned short* gA1 = gA0 + 16 * (long)lda;
  const unsigned short* gB0 = Bp + (long)(n0g + 32 * wave + rr) * ldb + cc;
  const unsigned short* gB1 = gB0 + 16 * (long)ldb;
  const int la0 = wave * 1024, la1 = wave * 1024 + 512;   // shorts; linear dest

  floatx16 acc[4][2] = {};
  const int sw = (lm >> 1) & 3;

  const int nt = K >> 5;                           // BK=32 tiles (K=1024 -> 32)

  // ---- prologue: stage t0 -> buf0, t1 -> buf1 (8 DMAs); retire t0's 4 ----
  ASYNC16(gA0, &As[0][la0]); ASYNC16(gA1, &As[0][la1]);
  ASYNC16(gB0, &Bs[0][la0]); ASYNC16(gB1, &Bs[0][la1]);
  gA0 += 32; gA1 += 32; gB0 += 32; gB1 += 32;
  ASYNC16(gA0, &As[1][la0]); ASYNC16(gA1, &As[1][la1]);
  ASYNC16(gB0, &Bs[1][la0]); ASYNC16(gB1, &Bs[1][la1]);
  gA0 += 32; gA1 += 32; gB0 += 32; gB1 += 32;
  WAITVM(4);                        // t0 resident; t1 in flight
  __builtin_amdgcn_s_barrier();

  // ---- main loop: 2 phases per BK=32 tile, 3-buf ring ----
  int bc = 0;                                      // buf of tile t
  for (int t = 0; t < nt; t++) {
    const int bs = (bc + 2 >= 3) ? bc - 1 : bc + 2;   // buf of t+2
    const bool pre = (t + 2 < nt);

    // ---- phase 0: af(i-pair 0) + bf(all); stage A(t+2) ----
    short8 af[2][2], bf[2][2];
#pragma unroll
    for (int i = 0; i < 2; i++)
#pragma unroll
      for (int s = 0; s < 2; s++)
        af[i][s] = *(const short8*)&As[bc][(wm + i * 32 + lm) * 32 + (((s * 2 + hi) ^ sw) * 8)];
#pragma unroll
    for (int j = 0; j < 2; j++)
#pragma unroll
      for (int s = 0; s < 2; s++)
        bf[j][s] = *(const short8*)&Bs[bc][(wn + j * 32 + lm) * 32 + (((s * 2 + hi) ^ sw) * 8)];
    if (pre) {
      ASYNC16(gA0, &As[bs][la0]); ASYNC16(gA1, &As[bs][la1]);
      gA0 += 32; gA1 += 32;
    }
    __builtin_amdgcn_s_barrier();
    asm volatile("s_waitcnt lgkmcnt(0)" ::: "memory");
    __builtin_amdgcn_s_setprio(1);
#pragma unroll
    for (int s = 0; s < 2; s++)
#pragma unroll
      for (int i = 0; i < 2; i++)
#pragma unroll
        for (int j = 0; j < 2; j++)
          acc[i][j] = __builtin_amdgcn_mfma_f32_32x32x16_bf16(af[i][s], bf[j][s], acc[i][j], 0, 0, 0);
    __builtin_amdgcn_s_setprio(0);
    __builtin_amdgcn_s_barrier();

    // ---- phase 1: af2(i-pair 1), bf carried in regs; stage B(t+2) ----
    short8 af2[2][2];
#pragma unroll
    for (int i = 0; i < 2; i++)
#pragma unroll
      for (int s = 0; s < 2; s++)
        af2[i][s] = *(const short8*)&As[bc][(wm + (2 + i) * 32 + lm) * 32 + (((s * 2 + hi) ^ sw) * 8)];
    if (pre) {
      ASYNC16(gB0, &Bs[bs][la0]); ASYNC16(gB1, &Bs[bs][la1]);
      gB0 += 32; gB1 += 32;
    }
    __builtin_amdgcn_s_barrier();
    asm volatile("s_waitcnt lgkmcnt(0)" ::: "memory");
    __builtin_amdgcn_s_setprio(1);
#pragma unroll
    for (int s = 0; s < 2; s++)
#pragma unroll
      for (int i = 0; i < 2; i++)
#pragma unroll
        for (int j = 0; j < 2; j++)
          acc[2 + i][j] = __builtin_amdgcn_mfma_f32_32x32x16_bf16(af2[i][s], bf[j][s], acc[2 + i][j], 0, 0, 0);
    __builtin_amdgcn_s_setprio(0);
    if (pre) { WAITVM(4); } else { WAITVM(0); }    // retire t+1's DMAs; keep t+2's in flight
    __builtin_amdgcn_s_barrier();
    bc = (bc == 2) ? 0 : bc + 1;
  }

  // ---- MODE 2/3: stage 1/rowsum for this block's 256 rows ----
  if (MODE == 2 || MODE == 3) {
    __syncthreads();
    if (tid < 256) invs[tid] = 1.0f / rowsum[zb * S_ + m0 + tid];
    __syncthreads();
  }

  // ---- epilogue: C/D col=lane&31, row=(r&3)+8*(r>>2)+4*hi ----
  if (NOUT == 3 && sel == 2) {
    // V output, stored transposed into Vt[B][DV][S]
    unsigned short* Vt = (unsigned short*)C;
    const int b = m0 >> 11;              // batch (2048 rows per batch; 256 | 2048)
    const int sbase = (m0 & 2047);
#pragma unroll
    for (int i = 0; i < 4; i++) {
      const int srowb = sbase + wm + i * 32 + (hi << 2);
#pragma unroll
      for (int j = 0; j < 2; j++) {
        const int col = n0 + wn + j * 32 + lm;
        const float bv = bias[col];
        unsigned short* vp = Vt + ((long)b * DV_ + col) * S_ + srowb;
#pragma unroll
        for (int g = 0; g < 4; g++) {
          ushort4 u;
          u.x = f2bf(acc[i][j][4 * g + 0] + bv);
          u.y = f2bf(acc[i][j][4 * g + 1] + bv);
          u.z = f2bf(acc[i][j][4 * g + 2] + bv);
          u.w = f2bf(acc[i][j][4 * g + 3] + bv);
          *(ushort4*)(vp + 8 * g) = u;
        }
      }
    }
  } else if (MODE == 1) {
    // scores: store U = exp(score), accumulate row sums (shfl-reduce + 1 atomic per 32 lanes)
#pragma unroll
    for (int i = 0; i < 4; i++) {
#pragma unroll
      for (int r = 0; r < 16; r++) {
        const int row = m0 + wm + i * 32 + (r & 3) + ((r >> 2) << 3) + (hi << 2);
        float sum2 = 0.f;
#pragma unroll
        for (int j = 0; j < 2; j++) {
          const int col = n0 + wn + j * 32 + lm;
          float e = __expf(acc[i][j][r] * scale);
          storeC(C + (long)row * N + col, e);
          sum2 += e;
        }
#pragma unroll
        for (int msk = 1; msk < 32; msk <<= 1) sum2 += __shfl_xor(sum2, msk, 64);
        if ((lane & 31) == 0) atomicAdd(&rowsum[zb * S_ + row], sum2);
      }
    }
  } else {
#pragma unroll
    for (int i = 0; i < 4; i++) {
#pragma unroll
      for (int j = 0; j < 2; j++) {
        const int col = n0 + wn + j * 32 + lm;
        const float bv = bias ? bias[col] : 0.f;
#pragma unroll
        for (int r = 0; r < 16; r++) {
          const int rl = wm + i * 32 + (r & 3) + ((r >> 2) << 3) + (hi << 2);
          float val = acc[i][j][r] * scale + bv;
          if (MODE == 3) {
            atomicAdd((float*)(C + (long)(m0 + rl) * N + col), val * invs[rl]);
          } else {
            if (MODE == 2) val *= invs[rl];
            storeC(C + (long)(m0 + rl) * N + col, val);
          }
        }
      }
    }
  }
}

extern "C" void kernel_launch(void* const* d_in, const int* in_sizes, int n_in,
                              void* d_out, int out_size, void* d_ws, size_t ws_size,
                              hipStream_t stream) {
  const float* q_in = (const float*)d_in[0];
  const float* k_in = (const float*)d_in[1];
  const float* v_in = (const float*)d_in[2];
  const float* Wq   = (const float*)d_in[3];
  const float* bq   = (const float*)d_in[4];
  const float* Wk   = (const float*)d_in[5];
  const float* bk   = (const float*)d_in[6];
  const float* Wv   = (const float*)d_in[7];
  const float* bv   = (const float*)d_in[8];
  float* out = (float*)d_out;

  // ---- workspace layout; U (bf16 scores) overlays dead qb/kb/vb after QKV ----
  char* ws = (char*)d_ws;
  const long nX = (long)B_ * S_ * D_;   // 8388608 elems
  const long nW = (long)D_ * DK_;       // 1048576
  unsigned short* qb  = (unsigned short*)(ws);
  unsigned short* kb  = qb + nX;
  unsigned short* vb  = kb + nX;
  unsigned short* WqT = vb + nX;        // 3 contiguous = B[3072,1024]
  unsigned short* Qb  = WqT + 3 * nW;
  unsigned short* Kb  = Qb + nX;
  unsigned short* Vt  = Kb + nX;        // [B, DV, S] written directly by QKV epilogue
  float*          rowsum = (float*)(Vt + nX);     // B*S fp32 = 32KB
  unsigned short* U   = (unsigned short*)ws;      // bf16 [B,S,S] overlay (qb/kb/vb dead)

  dim3 blk(256), blk5(512);

  // 0) zero rowsum + out (out receives split-K atomicAdd partials)
  hipMemsetAsync(rowsum, 0, (size_t)B_ * S_ * sizeof(float), stream);
  hipMemsetAsync(out, 0, (size_t)B_ * S_ * DV_ * sizeof(float), stream);

  // 1) prep: q/k/v -> bf16 and W -> W^T bf16, one dispatch
  {
    dim3 g(12288 + 3072);
    prep<<<g, blk, 0, stream>>>(q_in, k_in, v_in, Wq, Wk, Wv, qb, WqT);
  }
  // 2) fused QKV projection; V stored transposed into Vt.  grid 12x32 = 384 blocks
  {
    dim3 g(3 * DK_ / 256, (B_ * S_) / 256, 1);
    gemm_bt256<unsigned short, 3, 0, 1><<<g, blk5, 0, stream>>>(
        qb, kb, vb, WqT, Qb, Kb, Vt, bq, bk, bv, nullptr,
        DK_, D_, D_, D_, 0, 0, 0, 1.f);
  }
  // 3) U = exp(Q K^T / 32) -> bf16, + per-row sums.  grid 8x8x4 = 256 blocks (1/CU)
  {
    dim3 g(S_ / 256, S_ / 256, B_);
    gemm_bt256<unsigned short, 1, 1, 1><<<g, blk5, 0, stream>>>(
        Qb, nullptr, nullptr, Kb, U, nullptr, nullptr, nullptr, nullptr, nullptr, rowsum,
        S_, DK_, DK_, DK_, (long)S_ * DK_, (long)S_ * DK_, (long)S_ * S_, 0.03125f);
  }
  // 4) out += (U_khalf @ V_khalf) / rowsum, split-K=2.  grid 4x8x8 = 256 blocks (1/CU)
  {
    dim3 g(DV_ / 256, S_ / 256, B_ * 2);
    gemm_bt256<float, 1, 3, 2><<<g, blk5, 0, stream>>>(
        U, nullptr, nullptr, Vt, out, nullptr, nullptr, nullptr, nullptr, nullptr, rowsum,
        DV_, S_ / 2, S_, S_, (long)S_ * S_, (long)DV_ * S_, (long)S_ * DV_, 1.f);
  }
}

// Round 8
// 340.429 us; speedup vs baseline: 1.1461x; 1.0986x over previous
//
#include <hip/hip_runtime.h>
#include <stdint.h>

// Problem constants (B,S,D fixed by the reference)
#define B_  4
#define S_  2048
#define D_  1024
#define DK_ 1024
#define DV_ 1024

typedef __attribute__((ext_vector_type(8)))  short short8;    // 8 bf16 = 4 VGPRs (MFMA A/B frag)
typedef __attribute__((ext_vector_type(16))) float floatx16;  // 32x32 MFMA C/D frag

// async global->LDS DMA, 16B per lane, wave-uniform LDS base (lane scatters +lane*16B)
#define ASYNC16(gsrc, ldst)                                                        \
  __builtin_amdgcn_global_load_lds(                                                \
      (const __attribute__((address_space(1))) unsigned int*)(gsrc),               \
      (__attribute__((address_space(3))) unsigned int*)(ldst), 16, 0, 0)

#define WAITVM(N) asm volatile("s_waitcnt vmcnt(" #N ")" ::: "memory")

// round-to-nearest-even fp32 -> bf16
__device__ __forceinline__ unsigned short f2bf(float f) {
  union { float f; uint32_t u; } v; v.f = f;
  uint32_t r = v.u + 0x7fffu + ((v.u >> 16) & 1u);
  return (unsigned short)(r >> 16);
}

__device__ __forceinline__ float bf2f(unsigned short u) {
  union { uint32_t u; float f; } v; v.u = ((uint32_t)u) << 16;
  return v.f;
}

// ---------------- prep: fp32->bf16 for q/k/v  +  W^T (bf16), one dispatch ----------------
__global__ __launch_bounds__(256)
void prep(const float* __restrict__ q, const float* __restrict__ k, const float* __restrict__ v,
          const float* __restrict__ W0, const float* __restrict__ W1, const float* __restrict__ W2,
          unsigned short* __restrict__ qkv, unsigned short* __restrict__ WT) {
  const int bid = blockIdx.x, tid = threadIdx.x;
  if (bid < 12288) {
    const int t  = bid >> 12;         // tensor 0..2
    const int cb = bid & 4095;        // chunk within tensor
    const float* in = (t == 0) ? q : (t == 1) ? k : v;
    unsigned short* o = qkv + (long)t * ((long)B_ * S_ * D_);
    const int i0 = cb * 512 + tid;    // float4 index (512 per block)
    float4 v0 = ((const float4*)in)[i0];
    float4 v1 = ((const float4*)in)[i0 + 256];
    ushort4 u0, u1;
    u0.x = f2bf(v0.x); u0.y = f2bf(v0.y); u0.z = f2bf(v0.z); u0.w = f2bf(v0.w);
    u1.x = f2bf(v1.x); u1.y = f2bf(v1.y); u1.z = f2bf(v1.z); u1.w = f2bf(v1.w);
    ((ushort4*)o)[i0] = u0;
    ((ushort4*)o)[i0 + 256] = u1;
  } else {
    const int b2 = bid - 12288;
    const int w  = b2 >> 10;          // weight 0..2
    const int tl = b2 & 1023;         // 32x32 tile id
    const float* in = (w == 0) ? W0 : (w == 1) ? W1 : W2;
    unsigned short* o = WT + (long)w * D_ * DK_;
    __shared__ float tile[32][33];
    const int bx = (tl & 31) * 32, by = (tl >> 5) * 32;
    const int tx = tid & 31, ty = tid >> 5;
    for (int r = ty; r < 32; r += 8)
      tile[r][tx] = in[(long)(by + r) * DK_ + bx + tx];
    __syncthreads();
    for (int r = ty; r < 32; r += 8)
      o[(long)(bx + r) * D_ + by + tx] = f2bf(tile[tx][r]);
  }
}

__device__ __forceinline__ void storeC(float* p, float v)          { *p = v; }
__device__ __forceinline__ void storeC(unsigned short* p, float v) { *p = f2bf(v); }

// ---------------- rowsumk: rowsum[r] = sum(U[r][:]), one wave per row ----------------
// Replaces the scores-epilogue's 64-sequential-shfl-chain + atomics (r13 theory: that
// serialized reduce was ~10-20K cy on the critical path with 1 block/CU).  Here: 8192
// independent waves, one 6-step reduce each, BW-bound (~33.5MB / 6.3TBps ~= 6 us).
__global__ __launch_bounds__(256)
void rowsumk(const unsigned short* __restrict__ U, float* __restrict__ rowsum) {
  const int w    = (blockIdx.x << 2) + (threadIdx.x >> 6);   // wave id = flat row (B*S)
  const int lane = threadIdx.x & 63;
  const unsigned short* row = U + (long)w * S_;
  float s = 0.f;
#pragma unroll
  for (int it = 0; it < 4; it++) {
    short8 v = *(const short8*)(row + it * 512 + lane * 8);
#pragma unroll
    for (int e = 0; e < 8; e++) s += bf2f((unsigned short)v[e]);
  }
#pragma unroll
  for (int m = 1; m < 64; m <<= 1) s += __shfl_xor(s, m, 64);
  if (lane == 0) rowsum[w] = s;
}

// ---------------- combine: out = (out + P) / rowsum, float4 ----------------
__global__ __launch_bounds__(256)
void combine(float* __restrict__ out, const float* __restrict__ P,
             const float* __restrict__ rowsum) {
  const long k = (long)blockIdx.x * 256 + threadIdx.x;       // float4 index
  float4 a = ((const float4*)out)[k];
  float4 b = ((const float4*)P)[k];
  const float inv = 1.0f / rowsum[k >> 8];                   // (k*4)/DV_ = k/256
  float4 o;
  o.x = (a.x + b.x) * inv; o.y = (a.y + b.y) * inv;
  o.z = (a.z + b.z) * inv; o.w = (a.w + b.w) * inv;
  ((float4*)out)[k] = o;
}

// ---------------- bf16 BT GEMM, 256x256 tile, 8 waves, 3-buf ring, counted vmcnt ----------------
// ROUND 14 = ROUND 13 RESUBMIT (r7 bench died to container infra before any run; source
//   audited: launch args, barrier uniformity, bounds, overlay aliasing all check out).
// K-loop UNCHANGED from r12 (verified: QKV runs this loop at ~44-47 us/block =
//   780 TF-equiv, at the guide's m248v2 reference level for 256^2/K=1024).  The r12
//   post-mortem located the scores/PV 2x per-block gap in the EPILOGUES, not the loop:
//   scores' 64 serialized shfl-reduce chains + atomics; PV's 33.5M non-coalescing
//   global atomicAdds.  This round removes both (rowsumk + P-buffer + combine).
// MODE: 0 plain store (+bias if non-null, *scale);  1 store exp(val*scale) only.
// KSPL: K-split; kh=bzi&1 selects K-half and (kh==1) redirects C to C1 (separate buffer).
template <typename OutT, int NOUT, int MODE, int KSPL>
__global__ __launch_bounds__(512, 2)
void gemm_bt256(const unsigned short* __restrict__ A0, const unsigned short* __restrict__ A1,
                const unsigned short* __restrict__ A2, const unsigned short* __restrict__ Bm,
                OutT* __restrict__ C0, OutT* __restrict__ C1, OutT* __restrict__ C2,
                const float* __restrict__ b0, const float* __restrict__ b1,
                const float* __restrict__ b2,
                int N, int K, int lda, int ldb, long sA, long sB, long sC, float scale) {
  __shared__ __align__(16) unsigned short As[3][256 * 32];   // 16KB per buf
  __shared__ __align__(16) unsigned short Bs[3][256 * 32];
  const int tid  = threadIdx.x;
  const int lane = tid & 63, wave = tid >> 6;     // 8 waves
  const int wm = (wave >> 2) * 128;               // 2 M-waves
  const int wn = (wave & 3) * 64;                 // 4 N-waves
  const int lm = lane & 31;
  const int hi = lane >> 5;

  // ---- bijective XCD-chunk remap (8 XCDs; every grid here has total %8 == 0) ----
  const int gx = gridDim.x, gy = gridDim.y;
  const int T  = gx * gy * (int)gridDim.z;
  const int l  = blockIdx.x + gx * (blockIdx.y + gy * blockIdx.z);
  const int l2 = (l & 7) * (T >> 3) + (l >> 3);
  const int bxi = l2 % gx;
  const int byi = (l2 / gx) % gy;
  const int bzi = l2 / (gx * gy);

  const int  kh = (KSPL > 1) ? (bzi & (KSPL - 1)) : 0;
  const long zb = (KSPL > 1) ? (bzi >> 1) : bzi;
  const int m0  = byi * 256;
  const int n0g = bxi * 256;

  const unsigned short* A = A0;
  OutT* C = C0;
  const float* bias = b0;
  int n0 = n0g, sel = 0;
  if (NOUT == 3) {
    sel = n0g >> 10;
    n0 = n0g & 1023;
    if (sel == 1)      { A = A1; C = C1; bias = b1; }
    else if (sel == 2) { A = A2; C = C2; bias = b2; }
  }
  if (KSPL > 1 && kh) C = C1;          // K-half 1 writes its own partial buffer
  A += zb * sA + (long)kh * K;
  const unsigned short* Bp = Bm + zb * sB + (long)kh * K;
  C += zb * sC;

  // ---- staging: wave w owns rows [32w,32w+32); 2 DMAs per matrix per tile (16 rows each) ----
  const int rr = lane >> 2;
  const int cc = (((lane & 3) ^ ((lane >> 3) & 3)) * 8);    // 64B-line XOR swizzle on source
  const unsigned short* gA0 = A  + (long)(m0  + 32 * wave + rr) * lda + cc;
  const unsigned short* gA1 = gA0 + 16 * (long)lda;
  const unsigned short* gB0 = Bp + (long)(n0g + 32 * wave + rr) * ldb + cc;
  const unsigned short* gB1 = gB0 + 16 * (long)ldb;
  const int la0 = wave * 1024, la1 = wave * 1024 + 512;     // shorts; linear dest

  floatx16 acc[4][2] = {};
  const int sw = (lm >> 1) & 3;

  const int nt = K >> 5;                           // BK=32 tiles

  // ---- prologue: stage t0 -> buf0, t1 -> buf1 (8 DMAs); retire t0's 4 ----
  ASYNC16(gA0, &As[0][la0]); ASYNC16(gA1, &As[0][la1]);
  ASYNC16(gB0, &Bs[0][la0]); ASYNC16(gB1, &Bs[0][la1]);
  gA0 += 32; gA1 += 32; gB0 += 32; gB1 += 32;
  ASYNC16(gA0, &As[1][la0]); ASYNC16(gA1, &As[1][la1]);
  ASYNC16(gB0, &Bs[1][la0]); ASYNC16(gB1, &Bs[1][la1]);
  gA0 += 32; gA1 += 32; gB0 += 32; gB1 += 32;
  WAITVM(4);                        // t0 resident; t1 in flight
  __builtin_amdgcn_s_barrier();

  // ---- main loop: 2 phases per BK=32 tile, 3-buf ring, vmcnt never 0 in loop ----
  int bc = 0;                                      // buf of tile t
  for (int t = 0; t < nt; t++) {
    const int bs = (bc + 2 >= 3) ? bc - 1 : bc + 2;   // buf of t+2
    const bool pre = (t + 2 < nt);

    // ---- phase 0: af(i-pair 0) + bf(all); stage A(t+2) ----
    short8 af[2][2], bf[2][2];
#pragma unroll
    for (int i = 0; i < 2; i++)
#pragma unroll
      for (int s = 0; s < 2; s++)
        af[i][s] = *(const short8*)&As[bc][(wm + i * 32 + lm) * 32 + (((s * 2 + hi) ^ sw) * 8)];
#pragma unroll
    for (int j = 0; j < 2; j++)
#pragma unroll
      for (int s = 0; s < 2; s++)
        bf[j][s] = *(const short8*)&Bs[bc][(wn + j * 32 + lm) * 32 + (((s * 2 + hi) ^ sw) * 8)];
    if (pre) {
      ASYNC16(gA0, &As[bs][la0]); ASYNC16(gA1, &As[bs][la1]);
      gA0 += 32; gA1 += 32;
    }
    __builtin_amdgcn_s_barrier();
    asm volatile("s_waitcnt lgkmcnt(0)" ::: "memory");
    __builtin_amdgcn_s_setprio(1);
#pragma unroll
    for (int s = 0; s < 2; s++)
#pragma unroll
      for (int i = 0; i < 2; i++)
#pragma unroll
        for (int j = 0; j < 2; j++)
          acc[i][j] = __builtin_amdgcn_mfma_f32_32x32x16_bf16(af[i][s], bf[j][s], acc[i][j], 0, 0, 0);
    __builtin_amdgcn_s_setprio(0);
    __builtin_amdgcn_s_barrier();

    // ---- phase 1: af2(i-pair 1), bf carried in regs; stage B(t+2) ----
    short8 af2[2][2];
#pragma unroll
    for (int i = 0; i < 2; i++)
#pragma unroll
      for (int s = 0; s < 2; s++)
        af2[i][s] = *(const short8*)&As[bc][(wm + (2 + i) * 32 + lm) * 32 + (((s * 2 + hi) ^ sw) * 8)];
    if (pre) {
      ASYNC16(gB0, &Bs[bs][la0]); ASYNC16(gB1, &Bs[bs][la1]);
      gB0 += 32; gB1 += 32;
    }
    __builtin_amdgcn_s_barrier();
    asm volatile("s_waitcnt lgkmcnt(0)" ::: "memory");
    __builtin_amdgcn_s_setprio(1);
#pragma unroll
    for (int s = 0; s < 2; s++)
#pragma unroll
      for (int i = 0; i < 2; i++)
#pragma unroll
        for (int j = 0; j < 2; j++)
          acc[2 + i][j] = __builtin_amdgcn_mfma_f32_32x32x16_bf16(af2[i][s], bf[j][s], acc[2 + i][j], 0, 0, 0);
    __builtin_amdgcn_s_setprio(0);
    if (pre) { WAITVM(4); } else { WAITVM(0); }    // retire t+1's DMAs; keep t+2's in flight
    __builtin_amdgcn_s_barrier();
    bc = (bc == 2) ? 0 : bc + 1;
  }

  // ---- epilogue: C/D col=lane&31, row=(r&3)+8*(r>>2)+4*hi ----
  if (NOUT == 3 && sel == 2) {
    // V output, stored transposed into Vt[B][DV][S]
    unsigned short* Vt = (unsigned short*)C;
    const int b = m0 >> 11;              // batch (2048 rows per batch; 256 | 2048)
    const int sbase = (m0 & 2047);
#pragma unroll
    for (int i = 0; i < 4; i++) {
      const int srowb = sbase + wm + i * 32 + (hi << 2);
#pragma unroll
      for (int j = 0; j < 2; j++) {
        const int col = n0 + wn + j * 32 + lm;
        const float bv = bias[col];
        unsigned short* vp = Vt + ((long)b * DV_ + col) * S_ + srowb;
#pragma unroll
        for (int g = 0; g < 4; g++) {
          ushort4 u;
          u.x = f2bf(acc[i][j][4 * g + 0] + bv);
          u.y = f2bf(acc[i][j][4 * g + 1] + bv);
          u.z = f2bf(acc[i][j][4 * g + 2] + bv);
          u.w = f2bf(acc[i][j][4 * g + 3] + bv);
          *(ushort4*)(vp + 8 * g) = u;
        }
      }
    }
  } else if (MODE == 1) {
    // scores: store U = exp(score*scale) ONLY (rowsum moved to rowsumk kernel)
#pragma unroll
    for (int i = 0; i < 4; i++) {
#pragma unroll
      for (int j = 0; j < 2; j++) {
        const int col = n0 + wn + j * 32 + lm;
#pragma unroll
        for (int r = 0; r < 16; r++) {
          const int row = m0 + wm + i * 32 + (r & 3) + ((r >> 2) << 3) + (hi << 2);
          storeC(C + (long)row * N + col, __expf(acc[i][j][r] * scale));
        }
      }
    }
  } else {
#pragma unroll
    for (int i = 0; i < 4; i++) {
#pragma unroll
      for (int j = 0; j < 2; j++) {
        const int col = n0 + wn + j * 32 + lm;
        const float bv = bias ? bias[col] : 0.f;
#pragma unroll
        for (int r = 0; r < 16; r++) {
          const int rl = wm + i * 32 + (r & 3) + ((r >> 2) << 3) + (hi << 2);
          storeC(C + (long)(m0 + rl) * N + col, acc[i][j][r] * scale + bv);
        }
      }
    }
  }
}

extern "C" void kernel_launch(void* const* d_in, const int* in_sizes, int n_in,
                              void* d_out, int out_size, void* d_ws, size_t ws_size,
                              hipStream_t stream) {
  const float* q_in = (const float*)d_in[0];
  const float* k_in = (const float*)d_in[1];
  const float* v_in = (const float*)d_in[2];
  const float* Wq   = (const float*)d_in[3];
  const float* bq   = (const float*)d_in[4];
  const float* Wk   = (const float*)d_in[5];
  const float* bk   = (const float*)d_in[6];
  const float* Wv   = (const float*)d_in[7];
  const float* bv   = (const float*)d_in[8];
  float* out = (float*)d_out;

  // ---- workspace layout; U (bf16 scores) overlays dead qb/kb/vb after QKV;
  //      P (fp32 PV half-1 partial, 33.5MB) overlays dead Qb+Kb after scores ----
  char* ws = (char*)d_ws;
  const long nX = (long)B_ * S_ * D_;   // 8388608 elems
  const long nW = (long)D_ * DK_;       // 1048576
  unsigned short* qb  = (unsigned short*)(ws);
  unsigned short* kb  = qb + nX;
  unsigned short* vb  = kb + nX;
  unsigned short* WqT = vb + nX;        // 3 contiguous = B[3072,1024]
  unsigned short* Qb  = WqT + 3 * nW;
  unsigned short* Kb  = Qb + nX;
  unsigned short* Vt  = Kb + nX;        // [B, DV, S] written directly by QKV epilogue
  float*          rowsum = (float*)(Vt + nX);     // B*S fp32 = 32KB
  unsigned short* U   = (unsigned short*)ws;      // bf16 [B,S,S] overlay (qb/kb/vb dead)
  float*          P   = (float*)Qb;               // fp32 [B,S,DV] overlay (Qb/Kb dead after scores)

  dim3 blk(256), blk5(512);

  // 1) prep: q/k/v -> bf16 and W -> W^T bf16, one dispatch
  {
    dim3 g(12288 + 3072);
    prep<<<g, blk, 0, stream>>>(q_in, k_in, v_in, Wq, Wk, Wv, qb, WqT);
  }
  // 2) fused QKV projection; V stored transposed into Vt.  grid 12x32 = 384 blocks
  {
    dim3 g(3 * DK_ / 256, (B_ * S_) / 256, 1);
    gemm_bt256<unsigned short, 3, 0, 1><<<g, blk5, 0, stream>>>(
        qb, kb, vb, WqT, Qb, Kb, Vt, bq, bk, bv,
        DK_, D_, D_, D_, 0, 0, 0, 1.f);
  }
  // 3) U = exp(Q K^T / 32) -> bf16 (pure exp+store epilogue).  grid 8x8x4 = 256 blocks
  {
    dim3 g(S_ / 256, S_ / 256, B_);
    gemm_bt256<unsigned short, 1, 1, 1><<<g, blk5, 0, stream>>>(
        Qb, nullptr, nullptr, Kb, U, nullptr, nullptr, nullptr, nullptr, nullptr,
        S_, DK_, DK_, DK_, (long)S_ * DK_, (long)S_ * DK_, (long)S_ * S_, 0.03125f);
  }
  // 4) rowsum[r] = sum U[r][:]   (8192 waves, BW-bound ~6us)
  {
    dim3 g((B_ * S_) / 4);
    rowsumk<<<g, blk, 0, stream>>>(U, rowsum);
  }
  // 5) PV split-K=2, NO atomics: half0 -> out, half1 -> P (plain fp32 stores).
  //    grid 4x8x8 = 256 blocks (1/CU)
  {
    dim3 g(DV_ / 256, S_ / 256, B_ * 2);
    gemm_bt256<float, 1, 0, 2><<<g, blk5, 0, stream>>>(
        U, nullptr, nullptr, Vt, out, P, nullptr, nullptr, nullptr, nullptr,
        DV_, S_ / 2, S_, S_, (long)S_ * S_, (long)DV_ * S_, (long)S_ * DV_, 1.f);
  }
  // 6) out = (out + P) / rowsum   (float4, 8192 blocks)
  {
    dim3 g((B_ * S_ * DV_) / 4 / 256);
    combine<<<g, blk, 0, stream>>>(out, P, rowsum);
  }
}